// Round 11
// baseline (211.703 us; speedup 1.0000x reference)
//
#include <hip/hip_runtime.h>

#define HORIZON 28
#define GAMMA 0.1f
#define ROWS 2   // independent row-chains per thread (fills dependency stalls)

typedef __attribute__((ext_vector_type(8))) _Float16 half8;   // MFMA A/B frag (4 VGPR)
typedef __attribute__((ext_vector_type(2))) _Float16 half2t;
typedef __attribute__((ext_vector_type(4))) float f32x4;      // MFMA C/D frag
typedef __attribute__((ext_vector_type(2))) float fv2;        // packed-fp32 pair
typedef __attribute__((ext_vector_type(4))) unsigned int u32x4;

__global__ void __launch_bounds__(256) sir_kernel(
    const float* __restrict__ inputs,
    const float* __restrict__ W1,
    const float* __restrict__ b1,
    const float* __restrict__ W2,
    const float* __restrict__ b2,
    const float* __restrict__ W3,
    const float* __restrict__ b3,
    float* __restrict__ out,
    int nrows)
{
    __shared__ float sWs[32], sWi[32], sWr[32], sWb[32];     // W1 SoA + b1
    __shared__ __align__(16) f32x4 sState[ROWS][256];        // per-chain state exchange

    const int tid  = threadIdx.x;
    const int lane = tid & 63;
    const int wid  = tid >> 6;
    const int g    = lane >> 4;    // lane group = k-chunk (k = 8g..8g+7)
    const int c15  = lane & 15;    // MFMA col = data row within a 16-row tile

    if (tid < 32) {
        sWs[tid] = W1[tid];
        sWi[tid] = W1[32 + tid];
        sWr[tid] = W1[64 + tid];
        sWb[tid] = b1[tid];
    }
    __syncthreads();

    // This lane's 8 W1 columns as fp32 pairs -> persistent regs (v_pk_fma_f32 path)
    fv2 wps[4], wpi[4], wpr[4], wpb[4];
    #pragma unroll
    for (int p = 0; p < 4; ++p) {
        wps[p] = *reinterpret_cast<const fv2*>(&sWs[g*8 + 2*p]);
        wpi[p] = *reinterpret_cast<const fv2*>(&sWi[g*8 + 2*p]);
        wpr[p] = *reinterpret_cast<const fv2*>(&sWr[g*8 + 2*p]);
        wpb[p] = *reinterpret_cast<const fv2*>(&sWb[g*8 + 2*p]);
    }

    // Persistent A-frags: W2 fp16 hi + lo residual. lane: A[out=c15][k=8g+j] = W2[k][c15]
    half8 ahi, alo;
    {
        u32x4 uh, ul;
        #pragma unroll
        for (int jj = 0; jj < 4; ++jj) {
            const float we = W2[(g*8 + 2*jj    )*16 + c15];
            const float wo = W2[(g*8 + 2*jj + 1)*16 + c15];
            half2t hh; hh[0] = (_Float16)we; hh[1] = (_Float16)wo;       // RNE
            half2t hl; hl[0] = (_Float16)(we - (float)hh[0]);
            hl[1] = (_Float16)(wo - (float)hh[1]);
            uh[jj] = __builtin_bit_cast(unsigned int, hh);
            ul[jj] = __builtin_bit_cast(unsigned int, hl);
        }
        ahi = __builtin_bit_cast(half8, uh);
        alo = __builtin_bit_cast(half8, ul);
    }
    const f32x4 b2f = *reinterpret_cast<const f32x4*>(b2 + g*4);   // C-init
    const f32x4 w3f = *reinterpret_cast<const f32x4*>(W3 + g*4);   // outs 4g..4g+3
    const float b3v = b3[0];

    const int row0 = blockIdx.x * (256 * ROWS) + tid;   // chain q owns row0 + q*256
    if (row0 >= nrows) return;   // never taken at B=2^20 (wave stays intact)

    float s[ROWS], iv[ROWS], r[ROWS], rcpN[ROWS];
    #pragma unroll
    for (int q = 0; q < ROWS; ++q) {
        const float* p = inputs + ((long)(row0 + q * 256) * 8 + 7) * 3;
        s[q]  = p[0];
        iv[q] = p[1];
        r[q]  = p[2];
        rcpN[q] = 1.0f / (s[q] + iv[q] + r[q]);   // N conserved by SIR update
    }

    f32x4* const stA = &sState[0][wid * 64];
    f32x4* const stB = &sState[1][wid * 64];

    const fv2 zero2 = (fv2){0.0f, 0.0f};

    // one tile: L1 in fp32 (R7-exact), pack to fp16 B-frag, 2 MFMA, L3 partial
    auto tile = [&](float ss, float ii, float rr) -> float {
        const fv2 sv  = (fv2){ss, ss};
        const fv2 ivv = (fv2){ii, ii};
        const fv2 rv  = (fv2){rr, rr};
        u32x4 ub;
        #pragma unroll
        for (int pp = 0; pp < 4; ++pp) {
            fv2 h = __builtin_elementwise_fma(sv,  wps[pp], wpb[pp]);
            h = __builtin_elementwise_fma(ivv, wpi[pp], h);
            h = __builtin_elementwise_fma(rv,  wpr[pp], h);
            h = __builtin_elementwise_max(h, zero2);
            ub[pp] = __builtin_bit_cast(unsigned int,
                        __builtin_amdgcn_cvt_pkrtz(h[0], h[1]));
        }
        const half8 bh = __builtin_bit_cast(half8, ub);
        f32x4 acc = __builtin_amdgcn_mfma_f32_16x16x32_f16(ahi, bh, b2f, 0, 0, 0);
        acc = __builtin_amdgcn_mfma_f32_16x16x32_f16(alo, bh, acc, 0, 0, 0);
        float pz = fmaxf(acc[0], 0.0f) * w3f[0];
        pz = fmaf(fmaxf(acc[1], 0.0f), w3f[1], pz);
        pz = fmaf(fmaxf(acc[2], 0.0f), w3f[2], pz);
        pz = fmaf(fmaxf(acc[3], 0.0f), w3f[3], pz);
        return pz;
    };

    auto step2 = [&](float o[ROWS]) {
        // stage both chains' states (same-wave LDS; compiler inserts lgkmcnt)
        {
            f32x4 st0; st0[0] = s[0]; st0[1] = iv[0]; st0[2] = r[0]; st0[3] = 0.0f;
            stA[lane] = st0;
            f32x4 st1; st1[0] = s[1]; st1[1] = iv[1]; st1[2] = r[1]; st1[3] = 0.0f;
            stB[lane] = st1;
        }
        float z[ROWS][4];
        #pragma unroll
        for (int m = 0; m < 4; ++m) {
            const f32x4 smA = stA[c15 + m * 16];   // state of chain-0 row 16m+c15
            const f32x4 smB = stB[c15 + m * 16];   // state of chain-1 row 16m+c15
            float pzA = tile(smA[0], smA[1], smA[2]);
            float pzB = tile(smB[0], smB[1], smB[2]);
            pzA += __shfl_xor(pzA, 16, 64);
            pzB += __shfl_xor(pzB, 16, 64);
            pzA += __shfl_xor(pzA, 32, 64);
            pzB += __shfl_xor(pzB, 32, 64);
            z[0][m] = pzA;
            z[1][m] = pzB;
        }
        #pragma unroll
        for (int q = 0; q < ROWS; ++q) {
            // my row in chain q lives in tile m == g
            const float zz = (g == 0) ? z[q][0] : (g == 1) ? z[q][1]
                           : (g == 2) ? z[q][2] : z[q][3];
            const float zb = zz + b3v;
            // softplus (stable): max(z,0) + ln2*log2(1 + exp2(-|z|*log2e))
            const float t = __builtin_amdgcn_exp2f(-fabsf(zb) * 1.44269504088896341f);
            const float beta = fmaxf(zb, 0.0f)
                             + 0.69314718055994531f * __builtin_amdgcn_logf(1.0f + t);
            const float new_inf = beta * s[q] * iv[q] * rcpN[q];
            const float new_rec = GAMMA * iv[q];
            s[q]  = s[q] - new_inf;
            iv[q] = iv[q] + new_inf - new_rec;
            r[q]  = r[q] + new_rec;
            o[q]  = iv[q];
        }
    };

    #pragma unroll 1
    for (int tt = 0; tt < HORIZON / 4; ++tt) {
        float o0[ROWS], o1[ROWS], o2[ROWS], o3[ROWS];
        step2(o0);
        step2(o1);
        step2(o2);
        step2(o3);
        #pragma unroll
        for (int q = 0; q < ROWS; ++q) {
            float4 v;
            v.x = o0[q]; v.y = o1[q]; v.z = o2[q]; v.w = o3[q];
            *reinterpret_cast<float4*>(out + (long)(row0 + q * 256) * HORIZON + tt * 4) = v;
        }
    }
}

extern "C" void kernel_launch(void* const* d_in, const int* in_sizes, int n_in,
                              void* d_out, int out_size, void* d_ws, size_t ws_size,
                              hipStream_t stream) {
    const float* inputs = (const float*)d_in[0];
    const float* W1 = (const float*)d_in[1];
    const float* b1 = (const float*)d_in[2];
    const float* W2 = (const float*)d_in[3];
    const float* b2 = (const float*)d_in[4];
    const float* W3 = (const float*)d_in[5];
    const float* b3 = (const float*)d_in[6];
    float* out = (float*)d_out;

    const int nrows = in_sizes[0] / 24;   // (B, 8, 3) fp32
    const int rows_per_block = 256 * ROWS;
    const int grid = (nrows + rows_per_block - 1) / rows_per_block;
    sir_kernel<<<grid, 256, 0, stream>>>(inputs, W1, b1, W2, b2, W3, b3, out, nrows);
}

// Round 13
// 163.059 us; speedup vs baseline: 1.2983x; 1.2983x over previous
//
#include <hip/hip_runtime.h>

#define HORIZON 28
#define GAMMA 0.1f

typedef __attribute__((ext_vector_type(8))) _Float16 half8;   // MFMA A/B frag (4 VGPR)
typedef __attribute__((ext_vector_type(2))) _Float16 half2t;  // v_pk_*_f16 operand
typedef __attribute__((ext_vector_type(4))) float f32x4;      // MFMA C/D frag
typedef __attribute__((ext_vector_type(4))) unsigned int u32x4;

__global__ void __launch_bounds__(256) sir_kernel(
    const float* __restrict__ inputs,
    const float* __restrict__ W1,
    const float* __restrict__ b1,
    const float* __restrict__ W2,
    const float* __restrict__ b2,
    const float* __restrict__ W3,
    const float* __restrict__ b3,
    float* __restrict__ out,
    int nrows)
{
    __shared__ float sWs[32], sWi[32], sWr[32], sWb[32];   // W1 SoA + b1 (staging only)

    const int tid  = threadIdx.x;
    const int lane = tid & 63;
    const int g    = lane >> 4;    // lane group = k-chunk (k = 8g..8g+7); own tile = g
    const int c15  = lane & 15;    // MFMA col = data row within a 16-row tile

    if (tid < 32) {
        sWs[tid] = W1[tid];
        sWi[tid] = W1[32 + tid];
        sWr[tid] = W1[64 + tid];
        sWb[tid] = b1[tid];
    }
    __syncthreads();

    // This lane's 8 W1 columns as fp16 even/odd pairs -> v_pk_fma_f16 path
    half2t wps[4], wpi[4], wpr[4], wpb[4];
    #pragma unroll
    for (int p = 0; p < 4; ++p) {
        const int k0 = g*8 + 2*p;
        wps[p][0] = (_Float16)sWs[k0]; wps[p][1] = (_Float16)sWs[k0+1];
        wpi[p][0] = (_Float16)sWi[k0]; wpi[p][1] = (_Float16)sWi[k0+1];
        wpr[p][0] = (_Float16)sWr[k0]; wpr[p][1] = (_Float16)sWr[k0+1];
        wpb[p][0] = (_Float16)sWb[k0]; wpb[p][1] = (_Float16)sWb[k0+1];
    }

    // Persistent A-frags: W2 fp16 hi + lo residual. lane: A[out=c15][k=8g+j] = W2[k][c15]
    half8 ahi, alo;
    {
        u32x4 uh, ul;
        #pragma unroll
        for (int jj = 0; jj < 4; ++jj) {
            const float we = W2[(g*8 + 2*jj    )*16 + c15];
            const float wo = W2[(g*8 + 2*jj + 1)*16 + c15];
            half2t hh; hh[0] = (_Float16)we; hh[1] = (_Float16)wo;       // RNE
            half2t hl; hl[0] = (_Float16)(we - (float)hh[0]);
            hl[1] = (_Float16)(wo - (float)hh[1]);
            uh[jj] = __builtin_bit_cast(unsigned int, hh);
            ul[jj] = __builtin_bit_cast(unsigned int, hl);
        }
        ahi = __builtin_bit_cast(half8, uh);
        alo = __builtin_bit_cast(half8, ul);
    }
    const f32x4 b2f = *reinterpret_cast<const f32x4*>(b2 + g*4);   // C-init
    const f32x4 w3f = *reinterpret_cast<const f32x4*>(W3 + g*4);   // outs 4g..4g+3
    const float b3v = b3[0];

    const int row = blockIdx.x * 256 + tid;
    if (row >= nrows) return;   // never taken at B=2^20 (wave stays intact)

    const float* p = inputs + ((long)row * 8 + 7) * 3;
    float s  = p[0];
    float iv = p[1];
    float r  = p[2];
    const float rcpN = 1.0f / (s + iv + r);   // N conserved by SIR update

    // bpermute byte-addresses: tile m pulls from lane 16m + c15 (per-lane constant)
    const int adr0 = (c15     ) << 2;
    const int adr1 = (c15 + 16) << 2;
    const int adr2 = (c15 + 32) << 2;
    const int adr3 = (c15 + 48) << 2;

    const half2t z2 = (half2t){(_Float16)0.0f, (_Float16)0.0f};

    // one tile: fp16 L1 from packed state words {s,i} and {r,r}, 2 MFMA, L3 partial
    auto tile = [&](int wsi, int wr) -> float {
        const half2t siv = __builtin_bit_cast(half2t, wsi);
        const half2t rv  = __builtin_bit_cast(half2t, wr);          // {r, r}
        const half2t sv  = __builtin_shufflevector(siv, siv, 0, 0); // {s, s} (op_sel)
        const half2t vv  = __builtin_shufflevector(siv, siv, 1, 1); // {i, i}
        u32x4 ub;
        #pragma unroll
        for (int pp = 0; pp < 4; ++pp) {
            half2t h = __builtin_elementwise_fma(sv, wps[pp], wpb[pp]);
            h = __builtin_elementwise_fma(vv, wpi[pp], h);
            h = __builtin_elementwise_fma(rv, wpr[pp], h);
            h = __builtin_elementwise_max(h, z2);
            ub[pp] = __builtin_bit_cast(unsigned int, h);   // this IS the B-frag word
        }
        const half8 bh = __builtin_bit_cast(half8, ub);
        f32x4 acc = __builtin_amdgcn_mfma_f32_16x16x32_f16(ahi, bh, b2f, 0, 0, 0);
        acc = __builtin_amdgcn_mfma_f32_16x16x32_f16(alo, bh, acc, 0, 0, 0);
        float pz = fmaxf(acc[0], 0.0f) * w3f[0];
        pz = fmaf(fmaxf(acc[1], 0.0f), w3f[1], pz);
        pz = fmaf(fmaxf(acc[2], 0.0f), w3f[2], pz);
        pz = fmaf(fmaxf(acc[3], 0.0f), w3f[3], pz);
        return pz;
    };

    auto step = [&]() -> float {
        // publish state as 2 packed-fp16 words; register gather via ds_bpermute
        const int usi = __builtin_bit_cast(int, __builtin_amdgcn_cvt_pkrtz(s, iv));
        const int ur  = __builtin_bit_cast(int, __builtin_amdgcn_cvt_pkrtz(r, r));

        float z[4];
        {
            const int w0 = __builtin_amdgcn_ds_bpermute(adr0, usi);
            const int x0 = __builtin_amdgcn_ds_bpermute(adr0, ur);
            float pz = tile(w0, x0);
            pz += __shfl_xor(pz, 16, 64);
            pz += __shfl_xor(pz, 32, 64);
            z[0] = pz;
        }
        {
            const int w1 = __builtin_amdgcn_ds_bpermute(adr1, usi);
            const int x1 = __builtin_amdgcn_ds_bpermute(adr1, ur);
            float pz = tile(w1, x1);
            pz += __shfl_xor(pz, 16, 64);
            pz += __shfl_xor(pz, 32, 64);
            z[1] = pz;
        }
        {
            const int w2 = __builtin_amdgcn_ds_bpermute(adr2, usi);
            const int x2 = __builtin_amdgcn_ds_bpermute(adr2, ur);
            float pz = tile(w2, x2);
            pz += __shfl_xor(pz, 16, 64);
            pz += __shfl_xor(pz, 32, 64);
            z[2] = pz;
        }
        {
            const int w3v = __builtin_amdgcn_ds_bpermute(adr3, usi);
            const int x3 = __builtin_amdgcn_ds_bpermute(adr3, ur);
            float pz = tile(w3v, x3);
            pz += __shfl_xor(pz, 16, 64);
            pz += __shfl_xor(pz, 32, 64);
            z[3] = pz;
        }
        // my row = 16g + c15 -> z from tile m == g
        const float zz = (g == 0) ? z[0] : (g == 1) ? z[1] : (g == 2) ? z[2] : z[3];
        const float zb = zz + b3v;

        // softplus (stable): max(z,0) + ln2*log2(1 + exp2(-|z|*log2e))
        const float t = __builtin_amdgcn_exp2f(-fabsf(zb) * 1.44269504088896341f);
        const float beta = fmaxf(zb, 0.0f) + 0.69314718055994531f * __builtin_amdgcn_logf(1.0f + t);
        const float new_inf = beta * s * iv * rcpN;
        const float new_rec = GAMMA * iv;
        s  = s - new_inf;
        iv = iv + new_inf - new_rec;
        r  = r + new_rec;
        return iv;
    };

    const long obase = (long)row * HORIZON;
    #pragma unroll 1
    for (int tt = 0; tt < HORIZON / 4; ++tt) {
        float4 o;
        o.x = step();
        o.y = step();
        o.z = step();
        o.w = step();
        *reinterpret_cast<float4*>(out + obase + tt * 4) = o;
    }
}

extern "C" void kernel_launch(void* const* d_in, const int* in_sizes, int n_in,
                              void* d_out, int out_size, void* d_ws, size_t ws_size,
                              hipStream_t stream) {
    const float* inputs = (const float*)d_in[0];
    const float* W1 = (const float*)d_in[1];
    const float* b1 = (const float*)d_in[2];
    const float* W2 = (const float*)d_in[3];
    const float* b2 = (const float*)d_in[4];
    const float* W3 = (const float*)d_in[5];
    const float* b3 = (const float*)d_in[6];
    float* out = (float*)d_out;

    const int nrows = in_sizes[0] / 24;   // (B, 8, 3) fp32
    const int grid = (nrows + 255) / 256;
    sir_kernel<<<grid, 256, 0, stream>>>(inputs, W1, b1, W2, b2, W3, b3, out, nrows);
}

// Round 14
// 155.316 us; speedup vs baseline: 1.3630x; 1.0499x over previous
//
#include <hip/hip_runtime.h>

#define HORIZON 28
#define GAMMA 0.1f

typedef __attribute__((ext_vector_type(8))) _Float16 half8;   // MFMA A/B frag (4 VGPR)
typedef __attribute__((ext_vector_type(2))) _Float16 half2t;
typedef __attribute__((ext_vector_type(4))) float f32x4;      // MFMA C/D frag
typedef __attribute__((ext_vector_type(4))) unsigned int u32x4;

// guaranteed-packed fp16 ops (VOP3P), register-only so the scheduler can move them
__device__ __forceinline__ unsigned pk_fma(unsigned a, unsigned b, unsigned c) {
    unsigned d;
    asm("v_pk_fma_f16 %0, %1, %2, %3" : "=v"(d) : "v"(a), "v"(b), "v"(c));
    return d;
}
__device__ __forceinline__ unsigned pk_max(unsigned a, unsigned b) {
    unsigned d;
    asm("v_pk_max_f16 %0, %1, %2" : "=v"(d) : "v"(a), "v"(b));
    return d;
}
__device__ __forceinline__ unsigned splat_lo(unsigned x) {   // {x.lo, x.lo}
    return __builtin_amdgcn_perm(x, x, 0x05040504u);
}
__device__ __forceinline__ unsigned splat_hi(unsigned x) {   // {x.hi, x.hi}
    return __builtin_amdgcn_perm(x, x, 0x07060706u);
}

__global__ void __launch_bounds__(256) sir_kernel(
    const float* __restrict__ inputs,
    const float* __restrict__ W1,
    const float* __restrict__ b1,
    const float* __restrict__ W2,
    const float* __restrict__ b2,
    const float* __restrict__ W3,
    const float* __restrict__ b3,
    float* __restrict__ out,
    int nrows)
{
    __shared__ float sWs[32], sWi[32], sWr[32], sWb[32];       // W1 SoA + b1 (staging)
    __shared__ __align__(16) float sOut[4][64 * HORIZON];      // per-wave output staging

    const int tid  = threadIdx.x;
    const int lane = tid & 63;
    const int wid  = tid >> 6;
    const int g    = lane >> 4;    // lane group = k-chunk (k = 8g..8g+7); own tile = g
    const int c15  = lane & 15;    // MFMA col = data row within a 16-row tile

    if (tid < 32) {
        sWs[tid] = W1[tid];
        sWi[tid] = W1[32 + tid];
        sWr[tid] = W1[64 + tid];
        sWb[tid] = b1[tid];
    }
    __syncthreads();

    // This lane's 8 W1 columns as packed fp16 even/odd pairs (RNE, setup-only)
    unsigned wps[4], wpi[4], wpr[4], wpb[4];
    #pragma unroll
    for (int p = 0; p < 4; ++p) {
        const int k0 = g*8 + 2*p;
        half2t a, b, c, d;
        a[0] = (_Float16)sWs[k0]; a[1] = (_Float16)sWs[k0+1];
        b[0] = (_Float16)sWi[k0]; b[1] = (_Float16)sWi[k0+1];
        c[0] = (_Float16)sWr[k0]; c[1] = (_Float16)sWr[k0+1];
        d[0] = (_Float16)sWb[k0]; d[1] = (_Float16)sWb[k0+1];
        wps[p] = __builtin_bit_cast(unsigned, a);
        wpi[p] = __builtin_bit_cast(unsigned, b);
        wpr[p] = __builtin_bit_cast(unsigned, c);
        wpb[p] = __builtin_bit_cast(unsigned, d);
    }

    // Persistent A-frags: W2 fp16 hi + lo residual. lane: A[out=c15][k=8g+j] = W2[k][c15]
    half8 ahi, alo;
    {
        u32x4 uh, ul;
        #pragma unroll
        for (int jj = 0; jj < 4; ++jj) {
            const float we = W2[(g*8 + 2*jj    )*16 + c15];
            const float wo = W2[(g*8 + 2*jj + 1)*16 + c15];
            half2t hh; hh[0] = (_Float16)we; hh[1] = (_Float16)wo;       // RNE
            half2t hl; hl[0] = (_Float16)(we - (float)hh[0]);
            hl[1] = (_Float16)(wo - (float)hh[1]);
            uh[jj] = __builtin_bit_cast(unsigned, hh);
            ul[jj] = __builtin_bit_cast(unsigned, hl);
        }
        ahi = __builtin_bit_cast(half8, uh);
        alo = __builtin_bit_cast(half8, ul);
    }
    const f32x4 b2f = *reinterpret_cast<const f32x4*>(b2 + g*4);   // C-init
    const f32x4 w3f = *reinterpret_cast<const f32x4*>(W3 + g*4);   // outs 4g..4g+3
    const float b3v = b3[0];

    const int row = blockIdx.x * 256 + tid;
    if (row >= nrows) return;   // never taken at B=2^20 (wave stays intact)

    const float* p = inputs + ((long)row * 8 + 7) * 3;
    float s  = p[0];
    float iv = p[1];
    float r  = p[2];
    const float rcpN = 1.0f / (s + iv + r);   // N conserved by SIR update

    // bpermute byte-addresses: tile m pulls from lane 16m + c15 (per-lane constant)
    const int adr0 = (c15     ) << 2;
    const int adr1 = (c15 + 16) << 2;
    const int adr2 = (c15 + 32) << 2;
    const int adr3 = (c15 + 48) << 2;

    // one tile: packed-fp16 L1 from state words {s,i} and {r,r}, 2 MFMA, L3 partial
    auto tile = [&](int wsi, int wr) -> float {
        const unsigned svw = splat_lo((unsigned)wsi);   // {s, s}
        const unsigned vvw = splat_hi((unsigned)wsi);   // {i, i}
        const unsigned rvw = (unsigned)wr;              // already {r, r}
        u32x4 ub;
        #pragma unroll
        for (int pp = 0; pp < 4; ++pp) {
            unsigned h = pk_fma(svw, wps[pp], wpb[pp]);
            h = pk_fma(vvw, wpi[pp], h);
            h = pk_fma(rvw, wpr[pp], h);
            h = pk_max(h, 0u);
            ub[pp] = h;   // this IS the B-frag word {h1[k even], h1[k odd]}
        }
        const half8 bh = __builtin_bit_cast(half8, ub);
        f32x4 acc = __builtin_amdgcn_mfma_f32_16x16x32_f16(ahi, bh, b2f, 0, 0, 0);
        acc = __builtin_amdgcn_mfma_f32_16x16x32_f16(alo, bh, acc, 0, 0, 0);
        float pz = fmaxf(acc[0], 0.0f) * w3f[0];
        pz = fmaf(fmaxf(acc[1], 0.0f), w3f[1], pz);
        pz = fmaf(fmaxf(acc[2], 0.0f), w3f[2], pz);
        pz = fmaf(fmaxf(acc[3], 0.0f), w3f[3], pz);
        return pz;
    };

    auto step = [&]() -> float {
        // publish state as 2 packed-fp16 words; register gather via ds_bpermute
        const int usi = __builtin_bit_cast(int, __builtin_amdgcn_cvt_pkrtz(s, iv));
        const int ur  = __builtin_bit_cast(int, __builtin_amdgcn_cvt_pkrtz(r, r));

        float z[4];
        {
            const int w0 = __builtin_amdgcn_ds_bpermute(adr0, usi);
            const int x0 = __builtin_amdgcn_ds_bpermute(adr0, ur);
            float pz = tile(w0, x0);
            pz += __shfl_xor(pz, 16, 64);
            pz += __shfl_xor(pz, 32, 64);
            z[0] = pz;
        }
        {
            const int w1 = __builtin_amdgcn_ds_bpermute(adr1, usi);
            const int x1 = __builtin_amdgcn_ds_bpermute(adr1, ur);
            float pz = tile(w1, x1);
            pz += __shfl_xor(pz, 16, 64);
            pz += __shfl_xor(pz, 32, 64);
            z[1] = pz;
        }
        {
            const int w2 = __builtin_amdgcn_ds_bpermute(adr2, usi);
            const int x2 = __builtin_amdgcn_ds_bpermute(adr2, ur);
            float pz = tile(w2, x2);
            pz += __shfl_xor(pz, 16, 64);
            pz += __shfl_xor(pz, 32, 64);
            z[2] = pz;
        }
        {
            const int w3v = __builtin_amdgcn_ds_bpermute(adr3, usi);
            const int x3 = __builtin_amdgcn_ds_bpermute(adr3, ur);
            float pz = tile(w3v, x3);
            pz += __shfl_xor(pz, 16, 64);
            pz += __shfl_xor(pz, 32, 64);
            z[3] = pz;
        }
        // my row = 16g + c15 -> z from tile m == g
        const float zz = (g == 0) ? z[0] : (g == 1) ? z[1] : (g == 2) ? z[2] : z[3];
        const float zb = zz + b3v;

        // softplus (stable): max(z,0) + ln2*log2(1 + exp2(-|z|*log2e))
        const float t = __builtin_amdgcn_exp2f(-fabsf(zb) * 1.44269504088896341f);
        const float beta = fmaxf(zb, 0.0f) + 0.69314718055994531f * __builtin_amdgcn_logf(1.0f + t);
        const float new_inf = beta * s * iv * rcpN;
        const float new_rec = GAMMA * iv;
        s  = s - new_inf;
        iv = iv + new_inf - new_rec;
        r  = r + new_rec;
        return iv;
    };

    // run 28 steps, staging outputs in LDS (row-major [64][28] per wave)
    float* const sOutW = &sOut[wid][0];
    #pragma unroll 1
    for (int st = 0; st < HORIZON; ++st) {
        sOutW[lane * HORIZON + st] = step();
    }

    // coalesced writeback: wave's 64 rows are 64*28 contiguous floats in `out`
    const long gbase = (long)(blockIdx.x * 256 + wid * 64) * HORIZON;
    #pragma unroll
    for (int t = 0; t < 7; ++t) {
        const f32x4 v = *reinterpret_cast<const f32x4*>(&sOutW[t * 256 + lane * 4]);
        *reinterpret_cast<f32x4*>(out + gbase + t * 256 + lane * 4) = v;
    }
}

extern "C" void kernel_launch(void* const* d_in, const int* in_sizes, int n_in,
                              void* d_out, int out_size, void* d_ws, size_t ws_size,
                              hipStream_t stream) {
    const float* inputs = (const float*)d_in[0];
    const float* W1 = (const float*)d_in[1];
    const float* b1 = (const float*)d_in[2];
    const float* W2 = (const float*)d_in[3];
    const float* b2 = (const float*)d_in[4];
    const float* W3 = (const float*)d_in[5];
    const float* b3 = (const float*)d_in[6];
    float* out = (float*)d_out;

    const int nrows = in_sizes[0] / 24;   // (B, 8, 3) fp32
    const int grid = (nrows + 255) / 256;
    sir_kernel<<<grid, 256, 0, stream>>>(inputs, W1, b1, W2, b2, W3, b3, out, nrows);
}